// Round 5
// baseline (121.274 us; speedup 1.0000x reference)
//
#include <hip/hip_runtime.h>

#define BATCH   32
#define DIM     128
#define NBASES  8
#define SSTEPS  128
#define LDA     136   // padded row (shorts): 272 B stride -> 4-bank shift/row, 16B-aligned rows

typedef __attribute__((ext_vector_type(8))) short s8v;   // 8 bf16 (4 VGPR)
typedef __attribute__((ext_vector_type(4))) short s4v;   // 4 bf16 (8B packed store)
typedef __attribute__((ext_vector_type(4))) float f4v;   // MFMA acc

__device__ __forceinline__ f4v mf(s8v a, s8v b, f4v c) {
    return __builtin_amdgcn_mfma_f32_16x16x32_bf16(a, b, c, 0, 0, 0);
}
__device__ __forceinline__ s8v ld8(const short* p) {
    return *reinterpret_cast<const s8v*>(p);
}
__device__ __forceinline__ s4v ld4(const short* p) {
    return *reinterpret_cast<const s4v*>(p);
}
__device__ __forceinline__ void st4(short* p, s4v v) {
    *reinterpret_cast<s4v*>(p) = v;   // 8B-aligned at all call sites -> ds_write_b64
}
__device__ __forceinline__ float upbf(short h) {
    return __uint_as_float(((unsigned)(unsigned short)h) << 16);
}
// split fp32 -> bf16 hi + bf16 lo (truncation; dropped residual ~2^-16 rel)
__device__ __forceinline__ void splitbf(float v, short& hi, short& lo) {
    const unsigned u = __float_as_uint(v);
    hi = (short)(u >> 16);
    const float fh = __uint_as_float(u & 0xffff0000u);
    lo = (short)(__float_as_uint(v - fh) >> 16);
}

__device__ __forceinline__ void write_out(float* __restrict__ outF, int b, int sidx,
                                          int o, int c, float val,
                                          int interleaved, int out_size)
{
    if (interleaved) {
        const int oi = ((b * SSTEPS + sidx) * DIM + o) * 2 + c;
        if (oi < out_size) outF[oi] = val;
    } else if (c == 0) {
        const int oi = (b * SSTEPS + sidx) * DIM + o;
        if (oi < out_size) outF[oi] = val;
    }
}

// ---- full 128x128x128 split-bf16 MFMA matmul: 16 waves, wave = 32x32 tile ----
// A from "norm" planes (A[m][k] at m*LDA+k), B from "trans" planes
// (holding B^T: buf[n*LDA+k] = B[k][n]). acc[mi][ni] are 16x16 C tiles.
// TRO: accumulate normal-orientation acc. NMO: accumulate acct[ni][mi] = C^T
// tiles by swapping operand roles on the SAME fragments (no extra LDS reads).
template<bool TRO, bool NMO>
__device__ __forceinline__ void mm_full(const short* __restrict__ Ah,
                                        const short* __restrict__ Al,
                                        const short* __restrict__ Bh,
                                        const short* __restrict__ Bl,
                                        f4v acc[2][2], f4v acct[2][2],
                                        int mb, int nb, int lane)
{
    const int l15 = lane & 15, quad = lane >> 4;
    #pragma unroll
    for (int kk = 0; kk < DIM; kk += 32) {
        const int ko = kk + quad * 8;
        s8v ah[2], al[2], bh[2], bl[2];
        #pragma unroll
        for (int i = 0; i < 2; ++i) {
            ah[i] = ld8(Ah + (mb + i * 16 + l15) * LDA + ko);
            al[i] = ld8(Al + (mb + i * 16 + l15) * LDA + ko);
            bh[i] = ld8(Bh + (nb + i * 16 + l15) * LDA + ko);
            bl[i] = ld8(Bl + (nb + i * 16 + l15) * LDA + ko);
        }
        #pragma unroll
        for (int mi = 0; mi < 2; ++mi)
            #pragma unroll
            for (int ni = 0; ni < 2; ++ni) {
                if (TRO) {
                    acc[mi][ni] = mf(ah[mi], bh[ni], acc[mi][ni]);
                    acc[mi][ni] = mf(ah[mi], bl[ni], acc[mi][ni]);
                    acc[mi][ni] = mf(al[mi], bh[ni], acc[mi][ni]);
                }
                if (NMO) {
                    // (A*B)^T = B^T*A^T
                    acct[ni][mi] = mf(bh[ni], ah[mi], acct[ni][mi]);
                    acct[ni][mi] = mf(bl[ni], ah[mi], acct[ni][mi]);
                    acct[ni][mi] = mf(bh[ni], al[mi], acct[ni][mi]);
                }
            }
    }
}

// ======== prologue: K_sum/R_sum einsum on 256 blocks (all CUs) -> d_ws ========
// ws layout: Ksum[32][128][128] fp32, then Rsum[32][128][128] fp32 (4 MB total).
__global__ __launch_bounds__(256)
void sum_kr(const float* __restrict__ kco, const float* __restrict__ rco,
            const float* __restrict__ KB,  const float* __restrict__ RB,
            float* __restrict__ ws)
{
    const int b = blockIdx.x >> 3, s = blockIdx.x & 7, t = threadIdx.x;
    const int boff = s * 16 * DIM + t * 8;           // 16-row slice, 8 floats/thread
    float kc[NBASES], rc[NBASES];
    #pragma unroll
    for (int n = 0; n < NBASES; ++n) {
        kc[n] = kco[b * NBASES + n];
        rc[n] = rco[b * NBASES + n];
    }
    float4 ka = {0.f,0.f,0.f,0.f}, kb4 = {0.f,0.f,0.f,0.f};
    float4 ra = {0.f,0.f,0.f,0.f}, rb4 = {0.f,0.f,0.f,0.f};
    #pragma unroll
    for (int n = 0; n < NBASES; ++n) {
        const float4 k0 = *reinterpret_cast<const float4*>(KB + n * DIM * DIM + boff);
        const float4 k1 = *reinterpret_cast<const float4*>(KB + n * DIM * DIM + boff + 4);
        const float4 r0 = *reinterpret_cast<const float4*>(RB + n * DIM * DIM + boff);
        const float4 r1 = *reinterpret_cast<const float4*>(RB + n * DIM * DIM + boff + 4);
        ka.x += kc[n] * k0.x; ka.y += kc[n] * k0.y; ka.z += kc[n] * k0.z; ka.w += kc[n] * k0.w;
        kb4.x += kc[n] * k1.x; kb4.y += kc[n] * k1.y; kb4.z += kc[n] * k1.z; kb4.w += kc[n] * k1.w;
        ra.x += rc[n] * r0.x; ra.y += rc[n] * r0.y; ra.z += rc[n] * r0.z; ra.w += rc[n] * r0.w;
        rb4.x += rc[n] * r1.x; rb4.y += rc[n] * r1.y; rb4.z += rc[n] * r1.z; rb4.w += rc[n] * r1.w;
    }
    float* Ks = ws;
    float* Rs = ws + BATCH * DIM * DIM;
    *reinterpret_cast<float4*>(Ks + b * DIM * DIM + boff)     = ka;
    *reinterpret_cast<float4*>(Ks + b * DIM * DIM + boff + 4) = kb4;
    *reinterpret_cast<float4*>(Rs + b * DIM * DIM + boff)     = ra;
    *reinterpret_cast<float4*>(Rs + b * DIM * DIM + boff + 4) = rb4;
}

// ============ whole problem: 1 block = 1 batch, MFMA chain in LDS ============
// u-table layout: row = 2*slot + comp (comp 0 = real, 1 = imag), 16 slots.
// slot s holds u_s = M^s z, seeded with slot0 = z (u_0).
template<int PRE>
__global__ __launch_bounds__(1024) __attribute__((amdgpu_waves_per_eu(4, 4)))
void htg_mfma(const float* __restrict__ z0r, const float* __restrict__ z0i,
              const float* __restrict__ ts,  const float* __restrict__ kco,
              const float* __restrict__ rco, const float* __restrict__ alp,
              const float* __restrict__ bet, const float* __restrict__ KB,
              const float* __restrict__ RB,  const float* __restrict__ wsum,
              float* __restrict__ outF, int interleaved, int out_size)
{
    __shared__ short nm_hi[DIM * LDA], nm_lo[DIM * LDA];   // row-major planes
    __shared__ short tr_hi[DIM * LDA], tr_lo[DIM * LDA];   // transposed planes
    __shared__ short ht_hi[32 * LDA],  ht_lo[32 * LDA];    // u-table A (row = 2*slot+comp)
    // u-table B (window ping-pong) overlays tr, which is dead after stage 3.

    const int b = blockIdx.x, t = threadIdx.x;
    const int w = t >> 6, lane = t & 63;
    const int l15 = lane & 15, quad = lane >> 4;
    const f4v z4 = {0.f, 0.f, 0.f, 0.f};
    // 4x4 wave grid of 32x32 tiles
    const int mb = (w & 3) * 32, nb = (w >> 2) * 32;

    // ---- S1: Rsum -> trans planes (tr[c*LDA+r] = R[r][c]); Ksum -> norm planes;
    //          z -> ht slot 0 (rows 0,1) ----
    if (PRE) {
        const float* Ks = wsum + b * DIM * DIM;
        const float* Rs = wsum + BATCH * DIM * DIM + b * DIM * DIM;
        #pragma unroll
        for (int q = 0; q < 4; ++q) {
            const int e = q * 4096 + t * 4;
            const float4 k4 = *reinterpret_cast<const float4*>(Ks + e);
            const float4 r4 = *reinterpret_cast<const float4*>(Rs + e);
            const int r = e >> 7, c = e & 127;
            const float rr[4] = {r4.x, r4.y, r4.z, r4.w};
            const float kk[4] = {k4.x, k4.y, k4.z, k4.w};
            s4v kh, kl;
            #pragma unroll
            for (int j = 0; j < 4; ++j) {
                short hi, lo;
                splitbf(rr[j], hi, lo);
                tr_hi[(c + j) * LDA + r] = hi; tr_lo[(c + j) * LDA + r] = lo;
                splitbf(kk[j], hi, lo);
                kh[j] = hi; kl[j] = lo;
            }
            st4(&nm_hi[r * LDA + c], kh);
            st4(&nm_lo[r * LDA + c], kl);
        }
        if (t < 2 * DIM) {
            const int c = t >> 7, o = t & 127;
            const float zv = (c == 0) ? z0r[b * DIM + o] : z0i[b * DIM + o];
            short hi, lo; splitbf(zv, hi, lo);
            ht_hi[c * LDA + o] = hi; ht_lo[c * LDA + o] = lo;
        }
    } else {
        float rc[NBASES], kc[NBASES];
        #pragma unroll
        for (int n = 0; n < NBASES; ++n) {
            rc[n] = rco[b * NBASES + n];
            kc[n] = kco[b * NBASES + n];
        }
        #pragma unroll
        for (int q = 0; q < 4; ++q) {
            const int e = q * 4096 + t * 4;
            float4 r4 = {0.f, 0.f, 0.f, 0.f}, k4 = {0.f, 0.f, 0.f, 0.f};
            #pragma unroll
            for (int n = 0; n < NBASES; ++n) {
                const float4 rv = *reinterpret_cast<const float4*>(RB + n * DIM * DIM + e);
                const float4 kv = *reinterpret_cast<const float4*>(KB + n * DIM * DIM + e);
                r4.x += rc[n] * rv.x; r4.y += rc[n] * rv.y;
                r4.z += rc[n] * rv.z; r4.w += rc[n] * rv.w;
                k4.x += kc[n] * kv.x; k4.y += kc[n] * kv.y;
                k4.z += kc[n] * kv.z; k4.w += kc[n] * kv.w;
            }
            const int r = e >> 7, c = e & 127;
            const float rr[4] = {r4.x, r4.y, r4.z, r4.w};
            const float kk[4] = {k4.x, k4.y, k4.z, k4.w};
            s4v kh, kl;
            #pragma unroll
            for (int j = 0; j < 4; ++j) {
                short hi, lo;
                splitbf(rr[j], hi, lo);
                tr_hi[(c + j) * LDA + r] = hi; tr_lo[(c + j) * LDA + r] = lo;
                splitbf(kk[j], hi, lo);
                kh[j] = hi; kl[j] = lo;
            }
            st4(&nm_hi[r * LDA + c], kh);
            st4(&nm_lo[r * LDA + c], kl);
        }
        if (t < 2 * DIM) {
            const int c = t >> 7, o = t & 127;
            const float zv = (c == 0) ? z0r[b * DIM + o] : z0i[b * DIM + o];
            short hi, lo; splitbf(zv, hi, lo);
            ht_hi[c * LDA + o] = hi; ht_lo[c * LDA + o] = lo;
        }
    }
    __syncthreads();

    f4v acc[2][2], acct[2][2];
    float xsave[2][2][4];   // Op1: X tile (exact fp32); after Op2' epilogue: A1 tile

    // ---- Op1: gram = R^T@R (DUAL; gram symmetric so acct = gram at transposed
    //      lane positions). K-terms preloaded to regs BEFORE the mm so X can be
    //      written immediately after one barrier. ----
    float kd[2][2][4], kdT[2][2][4];
    #pragma unroll
    for (int mi = 0; mi < 2; ++mi)
        #pragma unroll
        for (int ni = 0; ni < 2; ++ni) {
            {   // normal tile: kd = K[row][col] - K[col][row]
                const int row0 = mb + mi * 16 + quad * 4;
                const int col  = nb + ni * 16 + l15;
                const s4v k2h = ld4(&nm_hi[col * LDA + row0]);
                const s4v k2l = ld4(&nm_lo[col * LDA + row0]);
                #pragma unroll
                for (int r = 0; r < 4; ++r)
                    kd[mi][ni][r] = (upbf(nm_hi[(row0 + r) * LDA + col]) +
                                     upbf(nm_lo[(row0 + r) * LDA + col]))
                                  - (upbf(k2h[r]) + upbf(k2l[r]));
            }
            {   // transposed tile (ti=mi, tj=ni): kdT = K[ct][rt] - K[rt][ct]
                const int rt0 = nb + mi * 16 + quad * 4;
                const int ct  = mb + ni * 16 + l15;
                const s4v k1h = ld4(&nm_hi[ct * LDA + rt0]);
                const s4v k1l = ld4(&nm_lo[ct * LDA + rt0]);
                #pragma unroll
                for (int r = 0; r < 4; ++r)
                    kdT[mi][ni][r] = (upbf(k1h[r]) + upbf(k1l[r]))
                                   - (upbf(nm_hi[(rt0 + r) * LDA + ct]) +
                                      upbf(nm_lo[(rt0 + r) * LDA + ct]));
            }
        }
    #pragma unroll
    for (int i = 0; i < 2; ++i)
        #pragma unroll
        for (int j = 0; j < 2; ++j) { acc[i][j] = z4; acct[i][j] = z4; }
    mm_full<true, true>(tr_hi, tr_lo, tr_hi, tr_lo, acc, acct, mb, nb, lane);
    __syncthreads();   // all K/R reads done (K was preloaded) -> safe to overwrite
    {
        const float alpha = alp[b], beta = bet[b], dtf = ts[0];
        // X -> tr (X^T layout, packed) + xsave
        #pragma unroll
        for (int mi = 0; mi < 2; ++mi)
            #pragma unroll
            for (int ni = 0; ni < 2; ++ni) {
                const int row0 = mb + mi * 16 + quad * 4;
                const int col  = nb + ni * 16 + l15;
                s4v h4, l4;
                #pragma unroll
                for (int r = 0; r < 4; ++r) {
                    float x = (alpha * kd[mi][ni][r] - beta * acc[mi][ni][r]) * dtf;
                    if (row0 + r == col) x += 1e-6f;
                    xsave[mi][ni][r] = x;
                    short hi, lo;
                    splitbf(x, hi, lo);
                    h4[r] = hi; l4[r] = lo;
                }
                st4(&tr_hi[col * LDA + row0], h4);        // X^T
                st4(&tr_lo[col * LDA + row0], l4);
            }
        // X -> nm (row-major, packed) from transposed tiles:
        // X[ct][rt0+r] = (alpha*kdT - beta*gram^T)*dt (+eps on diag)
        #pragma unroll
        for (int ti = 0; ti < 2; ++ti)
            #pragma unroll
            for (int tj = 0; tj < 2; ++tj) {
                const int rt0 = nb + ti * 16 + quad * 4;
                const int ct  = mb + tj * 16 + l15;
                s4v h4, l4;
                #pragma unroll
                for (int r = 0; r < 4; ++r) {
                    float x = (alpha * kdT[ti][tj][r] - beta * acct[ti][tj][r]) * dtf;
                    if (ct == rt0 + r) x += 1e-6f;
                    short hi, lo;
                    splitbf(x, hi, lo);
                    h4[r] = hi; l4[r] = lo;
                }
                st4(&nm_hi[ct * LDA + rt0], h4);          // X
                st4(&nm_lo[ct * LDA + rt0], l4);
            }
    }
    __syncthreads();

    // ---- Op2': C = X@X (+ C^T via DUAL); A2 = X/6 + C/24 -> trans;
    //      C -> norm (packed st4 from acct); A1 = I + X + C/2 -> xsave ----
    #pragma unroll
    for (int i = 0; i < 2; ++i)
        #pragma unroll
        for (int j = 0; j < 2; ++j) { acc[i][j] = z4; acct[i][j] = z4; }
    mm_full<true, true>(nm_hi, nm_lo, tr_hi, tr_lo, acc, acct, mb, nb, lane);
    __syncthreads();
    #pragma unroll
    for (int mi = 0; mi < 2; ++mi)
        #pragma unroll
        for (int ni = 0; ni < 2; ++ni) {
            const int row0 = mb + mi * 16 + quad * 4;
            const int col  = nb + ni * 16 + l15;
            s4v h4, l4;
            #pragma unroll
            for (int r = 0; r < 4; ++r) {
                const int row = row0 + r;
                const float xv = xsave[mi][ni][r];        // exact X (no LDS re-read)
                const float cv = acc[mi][ni][r];
                const float a2 = xv * (1.f / 6.f) + cv * (1.f / 24.f);
                xsave[mi][ni][r] = ((row == col) ? 1.f : 0.f) + xv + 0.5f * cv;  // A1
                short hi, lo;
                splitbf(a2, hi, lo);
                h4[r] = hi; l4[r] = lo;
            }
            st4(&tr_hi[col * LDA + row0], h4);        // A2^T
            st4(&tr_lo[col * LDA + row0], l4);
        }
    #pragma unroll
    for (int ti = 0; ti < 2; ++ti)
        #pragma unroll
        for (int tj = 0; tj < 2; ++tj) {
            const int rt0 = nb + ti * 16 + quad * 4;
            const int ct  = mb + tj * 16 + l15;
            s4v h4, l4;
            #pragma unroll
            for (int r = 0; r < 4; ++r) {
                short hi, lo;
                splitbf(acct[ti][tj][r], hi, lo);
                h4[r] = hi; l4[r] = lo;
            }
            st4(&nm_hi[ct * LDA + rt0], h4);          // C
            st4(&nm_lo[ct * LDA + rt0], l4);
        }
    __syncthreads();

    // ---- Op3': M = A1 + C@A2 (acc seeded with exact-fp32 A1) -> norm + trans ----
    #pragma unroll
    for (int mi = 0; mi < 2; ++mi)
        #pragma unroll
        for (int ni = 0; ni < 2; ++ni)
            #pragma unroll
            for (int r = 0; r < 4; ++r) acc[mi][ni][r] = xsave[mi][ni][r];
    mm_full<true, false>(nm_hi, nm_lo, tr_hi, tr_lo, acc, acct, mb, nb, lane);
    __syncthreads();
    #pragma unroll
    for (int mi = 0; mi < 2; ++mi)
        #pragma unroll
        for (int ni = 0; ni < 2; ++ni) {
            const int row0 = mb + mi * 16 + quad * 4;
            const int col  = nb + ni * 16 + l15;
            s4v h4, l4;
            #pragma unroll
            for (int r = 0; r < 4; ++r) {
                short hi, lo;
                splitbf(acc[mi][ni][r], hi, lo);
                nm_hi[(row0 + r) * LDA + col] = hi;   // M (scalar: A1^T not reg-local)
                nm_lo[(row0 + r) * LDA + col] = lo;
                h4[r] = hi; l4[r] = lo;
            }
            st4(&tr_hi[col * LDA + row0], h4);        // M^T
            st4(&tr_lo[col * LDA + row0], l4);
        }
    __syncthreads();

    // ---- seed stages 0..2 (W = M^J): FUSED {round + squaring}.
    //  round (waves 0..7): slots[J..2J) = W @ slots[0..J)
    //  sq (all 16 waves):  W <- W^2  (DUAL -> packed nm writes) ----
    #pragma unroll
    for (int stage = 0; stage < 3; ++stage) {
        const int J = 1 << stage;
        f4v ar = z4;
        #pragma unroll
        for (int i = 0; i < 2; ++i)
            #pragma unroll
            for (int j = 0; j < 2; ++j) { acc[i][j] = z4; acct[i][j] = z4; }
        if (w < 8) {
            #pragma unroll
            for (int kk = 0; kk < DIM; kk += 32) {
                const int ko = kk + quad * 8;
                const s8v rah = ld8(nm_hi + (w * 16 + l15) * LDA + ko);
                const s8v ral = ld8(nm_lo + (w * 16 + l15) * LDA + ko);
                const s8v rbh = ld8(ht_hi + l15 * LDA + ko);
                const s8v rbl = ld8(ht_lo + l15 * LDA + ko);
                ar = mf(rah, rbh, ar);
                ar = mf(rah, rbl, ar);
                ar = mf(ral, rbh, ar);
            }
        }
        mm_full<true, true>(nm_hi, nm_lo, tr_hi, tr_lo, acc, acct, mb, nb, lane);
        __syncthreads();
        if (w < 8 && l15 < 2 * J) {
            const int o0 = w * 16 + quad * 4;
            const int sidx = (l15 >> 1) + J - 1;
            s4v h4, l4;
            #pragma unroll
            for (int r = 0; r < 4; ++r) {
                short hi, lo;
                splitbf(ar[r], hi, lo);
                h4[r] = hi; l4[r] = lo;
                write_out(outF, b, sidx, o0 + r, l15 & 1, ar[r], interleaved, out_size);
            }
            st4(&ht_hi[(l15 + 2 * J) * LDA + o0], h4);
            st4(&ht_lo[(l15 + 2 * J) * LDA + o0], l4);
        }
        #pragma unroll
        for (int mi = 0; mi < 2; ++mi)
            #pragma unroll
            for (int ni = 0; ni < 2; ++ni) {
                const int row0 = mb + mi * 16 + quad * 4;
                const int col  = nb + ni * 16 + l15;
                s4v h4, l4;
                #pragma unroll
                for (int r = 0; r < 4; ++r) {
                    short hi, lo;
                    splitbf(acc[mi][ni][r], hi, lo);
                    h4[r] = hi; l4[r] = lo;
                }
                st4(&tr_hi[col * LDA + row0], h4);
                st4(&tr_lo[col * LDA + row0], l4);
            }
        #pragma unroll
        for (int ti = 0; ti < 2; ++ti)
            #pragma unroll
            for (int tj = 0; tj < 2; ++tj) {
                const int rt0 = nb + ti * 16 + quad * 4;
                const int ct  = mb + tj * 16 + l15;
                s4v h4, l4;
                #pragma unroll
                for (int r = 0; r < 4; ++r) {
                    short hi, lo;
                    splitbf(acct[ti][tj][r], hi, lo);
                    h4[r] = hi; l4[r] = lo;
                }
                st4(&nm_hi[ct * LDA + rt0], h4);
                st4(&nm_lo[ct * LDA + rt0], l4);
            }
        __syncthreads();
    }

    // ---- stage 3 (J=8): round + LAST squaring. Windows/tail never read M^16^T
    //      again -> NM-only squaring (24 MFMA/wave), no tr writes; tr dies here. ----
    {
        const int J = 8;
        f4v ar = z4;
        #pragma unroll
        for (int i = 0; i < 2; ++i)
            #pragma unroll
            for (int j = 0; j < 2; ++j) acct[i][j] = z4;
        if (w < 8) {
            #pragma unroll
            for (int kk = 0; kk < DIM; kk += 32) {
                const int ko = kk + quad * 8;
                const s8v rah = ld8(nm_hi + (w * 16 + l15) * LDA + ko);
                const s8v ral = ld8(nm_lo + (w * 16 + l15) * LDA + ko);
                const s8v rbh = ld8(ht_hi + l15 * LDA + ko);
                const s8v rbl = ld8(ht_lo + l15 * LDA + ko);
                ar = mf(rah, rbh, ar);
                ar = mf(rah, rbl, ar);
                ar = mf(ral, rbh, ar);
            }
        }
        mm_full<false, true>(nm_hi, nm_lo, tr_hi, tr_lo, acc, acct, mb, nb, lane);
        __syncthreads();
        if (w < 8 && l15 < 2 * J) {
            const int o0 = w * 16 + quad * 4;
            const int sidx = (l15 >> 1) + J - 1;
            s4v h4, l4;
            #pragma unroll
            for (int r = 0; r < 4; ++r) {
                short hi, lo;
                splitbf(ar[r], hi, lo);
                h4[r] = hi; l4[r] = lo;
                write_out(outF, b, sidx, o0 + r, l15 & 1, ar[r], interleaved, out_size);
            }
            st4(&ht_hi[(l15 + 2 * J) * LDA + o0], h4);
            st4(&ht_lo[(l15 + 2 * J) * LDA + o0], l4);
        }
        #pragma unroll
        for (int ti = 0; ti < 2; ++ti)
            #pragma unroll
            for (int tj = 0; tj < 2; ++tj) {
                const int rt0 = nb + ti * 16 + quad * 4;
                const int ct  = mb + tj * 16 + l15;
                s4v h4, l4;
                #pragma unroll
                for (int r = 0; r < 4; ++r) {
                    short hi, lo;
                    splitbf(acct[ti][tj][r], hi, lo);
                    h4[r] = hi; l4[r] = lo;
                }
                st4(&nm_hi[ct * LDA + rt0], h4);      // V = M^16
                st4(&nm_lo[ct * LDA + rt0], l4);
            }
        __syncthreads();
    }

    // ---- 8 windows: rows <- V @ rows, ping-pong htA <-> htB (htB on dead tr).
    //      ONE barrier per window. Window 8 = tail (u_128 only, no LDS writes).
    //      16 waves, 1 16x16 tile each; V A-frags cached in registers. ----
    const int sw = w >> 1, ct = w & 1;          // strip (rows), col-tile
    s8v vah[4], val[4];
    #pragma unroll
    for (int k4 = 0; k4 < 4; ++k4) {
        const int ko = k4 * 32 + quad * 8;
        vah[k4] = ld8(nm_hi + (sw * 16 + l15) * LDA + ko);
        val[k4] = ld8(nm_lo + (sw * 16 + l15) * LDA + ko);
    }
    short *rh_hi = ht_hi, *rh_lo = ht_lo;       // read buffer
    short *wh_hi = tr_hi, *wh_lo = tr_lo;       // write buffer (overlay on tr)
    #pragma unroll
    for (int q = 1; q <= 8; ++q) {
        f4v a2 = z4;
        #pragma unroll
        for (int k4 = 0; k4 < 4; ++k4) {
            const int ko = k4 * 32 + quad * 8;
            const s8v bh = ld8(rh_hi + (ct * 16 + l15) * LDA + ko);
            const s8v bl = ld8(rh_lo + (ct * 16 + l15) * LDA + ko);
            a2 = mf(vah[k4], bh, a2);
            a2 = mf(vah[k4], bl, a2);
            a2 = mf(val[k4], bh, a2);
        }
        {
            const int o0 = sw * 16 + quad * 4;
            const int n = ct * 16 + l15;
            const int sidx = 16 * q + (n >> 1) - 1;
            s4v h4, l4;
            #pragma unroll
            for (int r = 0; r < 4; ++r) {
                short hi, lo;
                splitbf(a2[r], hi, lo);
                h4[r] = hi; l4[r] = lo;
                if (sidx < SSTEPS)
                    write_out(outF, b, sidx, o0 + r, n & 1, a2[r], interleaved, out_size);
            }
            if (q < 8) {
                st4(&wh_hi[n * LDA + o0], h4);
                st4(&wh_lo[n * LDA + o0], l4);
            }
        }
        __syncthreads();
        short* tp;
        tp = rh_hi; rh_hi = wh_hi; wh_hi = tp;
        tp = rh_lo; rh_lo = wh_lo; wh_lo = tp;
    }
}

// ================= host =================
extern "C" void kernel_launch(void* const* d_in, const int* in_sizes, int n_in,
                              void* d_out, int out_size, void* d_ws, size_t ws_size,
                              hipStream_t stream)
{
    (void)in_sizes; (void)n_in;
    const float* z0r = (const float*)d_in[0];
    const float* z0i = (const float*)d_in[1];
    const float* ts  = (const float*)d_in[2];
    const float* kco = (const float*)d_in[3];
    const float* rco = (const float*)d_in[4];
    const float* alp = (const float*)d_in[5];
    const float* bet = (const float*)d_in[6];
    const float* KB  = (const float*)d_in[7];
    const float* RB  = (const float*)d_in[8];
    float* outF = (float*)d_out;

    const int interleaved = (out_size >= 2 * BATCH * SSTEPS * DIM) ? 1 : 0;
    const size_t ws_needed = (size_t)2 * BATCH * DIM * DIM * sizeof(float);  // 4 MB

    if (d_ws != nullptr && ws_size >= ws_needed) {
        float* ws = (float*)d_ws;
        sum_kr<<<dim3(BATCH * 8), dim3(256), 0, stream>>>(kco, rco, KB, RB, ws);
        htg_mfma<1><<<dim3(BATCH), dim3(1024), 0, stream>>>(
            z0r, z0i, ts, kco, rco, alp, bet, KB, RB, ws, outF, interleaved, out_size);
    } else {
        htg_mfma<0><<<dim3(BATCH), dim3(1024), 0, stream>>>(
            z0r, z0i, ts, kco, rco, alp, bet, KB, RB, nullptr, outF, interleaved, out_size);
    }
}

// Round 6
// 120.073 us; speedup vs baseline: 1.0100x; 1.0100x over previous
//
#include <hip/hip_runtime.h>

#define BATCH   32
#define DIM     128
#define NBASES  8
#define SSTEPS  128
#define LDA     136   // padded row (shorts): 272 B stride, 16B-aligned rows

typedef __attribute__((ext_vector_type(8)))  short s8v;   // 8 bf16 (4 VGPR)
typedef __attribute__((ext_vector_type(4)))  short s4v;   // 4 bf16 (8B packed store)
typedef __attribute__((ext_vector_type(4)))  float f4v;   // 16x16 MFMA acc
typedef __attribute__((ext_vector_type(16))) float f16v;  // 32x32 MFMA acc

__device__ __forceinline__ f4v mf(s8v a, s8v b, f4v c) {
    return __builtin_amdgcn_mfma_f32_16x16x32_bf16(a, b, c, 0, 0, 0);
}
__device__ __forceinline__ f16v mf32(s8v a, s8v b, f16v c) {
    return __builtin_amdgcn_mfma_f32_32x32x16_bf16(a, b, c, 0, 0, 0);
}
__device__ __forceinline__ s8v ld8(const short* p) {
    return *reinterpret_cast<const s8v*>(p);
}
__device__ __forceinline__ s4v ld4(const short* p) {
    return *reinterpret_cast<const s4v*>(p);
}
__device__ __forceinline__ void st4(short* p, s4v v) {
    *reinterpret_cast<s4v*>(p) = v;   // 8B-aligned at all call sites -> ds_write_b64
}
__device__ __forceinline__ float upbf(short h) {
    return __uint_as_float(((unsigned)(unsigned short)h) << 16);
}
// split fp32 -> bf16 hi + bf16 lo (truncation; dropped residual ~2^-16 rel)
__device__ __forceinline__ void splitbf(float v, short& hi, short& lo) {
    const unsigned u = __float_as_uint(v);
    hi = (short)(u >> 16);
    const float fh = __uint_as_float(u & 0xffff0000u);
    lo = (short)(__float_as_uint(v - fh) >> 16);
}

__device__ __forceinline__ void write_out(float* __restrict__ outF, int b, int sidx,
                                          int o, int c, float val,
                                          int interleaved, int out_size)
{
    if (interleaved) {
        const int oi = ((b * SSTEPS + sidx) * DIM + o) * 2 + c;
        if (oi < out_size) outF[oi] = val;
    } else if (c == 0) {
        const int oi = (b * SSTEPS + sidx) * DIM + o;
        if (oi < out_size) outF[oi] = val;
    }
}

// ---- full 128x128x128 split-bf16 MFMA matmul: 16 waves, wave = one 32x32
// v_mfma_f32_32x32x16_bf16 tile. A row-major from "norm" planes, B^T from
// "trans" planes. TRO: acc = C tile. NMO: acct = C^T tile (operand swap on
// the SAME loaded fragments -> no extra LDS reads).
// Fragment mapping: row/col = lane&31, k-octet = (lane>>5)*8.
// C/D layout (m74/m101): col = lane&31, row = (reg&3) + 8*(reg>>2) + 4*(lane>>5).
template<bool TRO, bool NMO>
__device__ __forceinline__ void mm32(const short* __restrict__ Ah,
                                     const short* __restrict__ Al,
                                     const short* __restrict__ Bh,
                                     const short* __restrict__ Bl,
                                     f16v& acc, f16v& acct,
                                     int mb, int nb, int lane)
{
    const int l31 = lane & 31, koc = (lane >> 5) * 8;
    #pragma unroll
    for (int ks = 0; ks < 8; ++ks) {
        const int ko = ks * 16 + koc;
        const s8v ah = ld8(Ah + (mb + l31) * LDA + ko);
        const s8v al = ld8(Al + (mb + l31) * LDA + ko);
        const s8v bh = ld8(Bh + (nb + l31) * LDA + ko);
        const s8v bl = ld8(Bl + (nb + l31) * LDA + ko);
        if (TRO) {
            acc = mf32(ah, bh, acc);
            acc = mf32(ah, bl, acc);
            acc = mf32(al, bh, acc);
        }
        if (NMO) {
            acct = mf32(bh, ah, acct);
            acct = mf32(bl, ah, acct);
            acct = mf32(bh, al, acct);
        }
    }
}

// ======== prologue: K_sum/R_sum einsum on 256 blocks (all CUs) -> d_ws ========
__global__ __launch_bounds__(256)
void sum_kr(const float* __restrict__ kco, const float* __restrict__ rco,
            const float* __restrict__ KB,  const float* __restrict__ RB,
            float* __restrict__ ws)
{
    const int b = blockIdx.x >> 3, s = blockIdx.x & 7, t = threadIdx.x;
    const int boff = s * 16 * DIM + t * 8;
    float kc[NBASES], rc[NBASES];
    #pragma unroll
    for (int n = 0; n < NBASES; ++n) {
        kc[n] = kco[b * NBASES + n];
        rc[n] = rco[b * NBASES + n];
    }
    float4 ka = {0.f,0.f,0.f,0.f}, kb4 = {0.f,0.f,0.f,0.f};
    float4 ra = {0.f,0.f,0.f,0.f}, rb4 = {0.f,0.f,0.f,0.f};
    #pragma unroll
    for (int n = 0; n < NBASES; ++n) {
        const float4 k0 = *reinterpret_cast<const float4*>(KB + n * DIM * DIM + boff);
        const float4 k1 = *reinterpret_cast<const float4*>(KB + n * DIM * DIM + boff + 4);
        const float4 r0 = *reinterpret_cast<const float4*>(RB + n * DIM * DIM + boff);
        const float4 r1 = *reinterpret_cast<const float4*>(RB + n * DIM * DIM + boff + 4);
        ka.x += kc[n] * k0.x; ka.y += kc[n] * k0.y; ka.z += kc[n] * k0.z; ka.w += kc[n] * k0.w;
        kb4.x += kc[n] * k1.x; kb4.y += kc[n] * k1.y; kb4.z += kc[n] * k1.z; kb4.w += kc[n] * k1.w;
        ra.x += rc[n] * r0.x; ra.y += rc[n] * r0.y; ra.z += rc[n] * r0.z; ra.w += rc[n] * r0.w;
        rb4.x += rc[n] * r1.x; rb4.y += rc[n] * r1.y; rb4.z += rc[n] * r1.z; rb4.w += rc[n] * r1.w;
    }
    float* Ks = ws;
    float* Rs = ws + BATCH * DIM * DIM;
    *reinterpret_cast<float4*>(Ks + b * DIM * DIM + boff)     = ka;
    *reinterpret_cast<float4*>(Ks + b * DIM * DIM + boff + 4) = kb4;
    *reinterpret_cast<float4*>(Rs + b * DIM * DIM + boff)     = ra;
    *reinterpret_cast<float4*>(Rs + b * DIM * DIM + boff + 4) = rb4;
}

// ============ whole problem: 1 block = 1 batch, MFMA chain in LDS ============
template<int PRE>
__global__ __launch_bounds__(1024) __attribute__((amdgpu_waves_per_eu(4, 4)))
void htg_mfma(const float* __restrict__ z0r, const float* __restrict__ z0i,
              const float* __restrict__ ts,  const float* __restrict__ kco,
              const float* __restrict__ rco, const float* __restrict__ alp,
              const float* __restrict__ bet, const float* __restrict__ KB,
              const float* __restrict__ RB,  const float* __restrict__ wsum,
              float* __restrict__ outF, int interleaved, int out_size)
{
    __shared__ short nm_hi[DIM * LDA], nm_lo[DIM * LDA];   // row-major planes
    __shared__ short tr_hi[DIM * LDA], tr_lo[DIM * LDA];   // transposed planes
    __shared__ short ht_hi[32 * LDA],  ht_lo[32 * LDA];    // u-table A

    const int b = blockIdx.x, t = threadIdx.x;
    const int w = t >> 6, lane = t & 63;
    const int l15 = lane & 15, quad = lane >> 4;            // 16x16 paths
    const int l31 = lane & 31, kq = lane >> 5;              // 32x32 paths
    const f4v z4 = {0.f, 0.f, 0.f, 0.f};
    const int mb = (w & 3) * 32, nb = (w >> 2) * 32;        // 4x4 grid of 32x32

    // ---- S1: Rsum -> trans planes; Ksum -> norm planes; z -> ht slot 0 ----
    if (PRE) {
        const float* Ks = wsum + b * DIM * DIM;
        const float* Rs = wsum + BATCH * DIM * DIM + b * DIM * DIM;
        #pragma unroll
        for (int q = 0; q < 4; ++q) {
            const int e = q * 4096 + t * 4;
            const float4 k4 = *reinterpret_cast<const float4*>(Ks + e);
            const float4 r4 = *reinterpret_cast<const float4*>(Rs + e);
            const int r = e >> 7, c = e & 127;
            const float rr[4] = {r4.x, r4.y, r4.z, r4.w};
            const float kk[4] = {k4.x, k4.y, k4.z, k4.w};
            s4v kh, kl;
            #pragma unroll
            for (int j = 0; j < 4; ++j) {
                short hi, lo;
                splitbf(rr[j], hi, lo);
                tr_hi[(c + j) * LDA + r] = hi; tr_lo[(c + j) * LDA + r] = lo;
                splitbf(kk[j], hi, lo);
                kh[j] = hi; kl[j] = lo;
            }
            st4(&nm_hi[r * LDA + c], kh);
            st4(&nm_lo[r * LDA + c], kl);
        }
        if (t < 2 * DIM) {
            const int c = t >> 7, o = t & 127;
            const float zv = (c == 0) ? z0r[b * DIM + o] : z0i[b * DIM + o];
            short hi, lo; splitbf(zv, hi, lo);
            ht_hi[c * LDA + o] = hi; ht_lo[c * LDA + o] = lo;
        }
    } else {
        float rc[NBASES], kc[NBASES];
        #pragma unroll
        for (int n = 0; n < NBASES; ++n) {
            rc[n] = rco[b * NBASES + n];
            kc[n] = kco[b * NBASES + n];
        }
        #pragma unroll
        for (int q = 0; q < 4; ++q) {
            const int e = q * 4096 + t * 4;
            float4 r4 = {0.f, 0.f, 0.f, 0.f}, k4 = {0.f, 0.f, 0.f, 0.f};
            #pragma unroll
            for (int n = 0; n < NBASES; ++n) {
                const float4 rv = *reinterpret_cast<const float4*>(RB + n * DIM * DIM + e);
                const float4 kv = *reinterpret_cast<const float4*>(KB + n * DIM * DIM + e);
                r4.x += rc[n] * rv.x; r4.y += rc[n] * rv.y;
                r4.z += rc[n] * rv.z; r4.w += rc[n] * rv.w;
                k4.x += kc[n] * kv.x; k4.y += kc[n] * kv.y;
                k4.z += kc[n] * kv.z; k4.w += kc[n] * kv.w;
            }
            const int r = e >> 7, c = e & 127;
            const float rr[4] = {r4.x, r4.y, r4.z, r4.w};
            const float kk[4] = {k4.x, k4.y, k4.z, k4.w};
            s4v kh, kl;
            #pragma unroll
            for (int j = 0; j < 4; ++j) {
                short hi, lo;
                splitbf(rr[j], hi, lo);
                tr_hi[(c + j) * LDA + r] = hi; tr_lo[(c + j) * LDA + r] = lo;
                splitbf(kk[j], hi, lo);
                kh[j] = hi; kl[j] = lo;
            }
            st4(&nm_hi[r * LDA + c], kh);
            st4(&nm_lo[r * LDA + c], kl);
        }
        if (t < 2 * DIM) {
            const int c = t >> 7, o = t & 127;
            const float zv = (c == 0) ? z0r[b * DIM + o] : z0i[b * DIM + o];
            short hi, lo; splitbf(zv, hi, lo);
            ht_hi[c * LDA + o] = hi; ht_lo[c * LDA + o] = lo;
        }
    }
    __syncthreads();

    f16v acc, acct;
    float xsave[16];    // Op1: X tile; after Op2': A1 tile
    float xsaveT[16];   // Op1: X^T tile; after Op2': A1^T tile

    // ---- Op1: gram = R^T@R (dual). K-diff terms preloaded to regs pre-mm. ----
    float kd[4][4], kdT[4][4];
    #pragma unroll
    for (int r4 = 0; r4 < 4; ++r4) {
        {   // normal tile: kd = K[row][col] - K[col][row]
            const int row0 = mb + 8 * r4 + 4 * kq;
            const int col  = nb + l31;
            const s4v k2h = ld4(&nm_hi[col * LDA + row0]);
            const s4v k2l = ld4(&nm_lo[col * LDA + row0]);
            #pragma unroll
            for (int j = 0; j < 4; ++j)
                kd[r4][j] = (upbf(nm_hi[(row0 + j) * LDA + col]) +
                             upbf(nm_lo[(row0 + j) * LDA + col]))
                          - (upbf(k2h[j]) + upbf(k2l[j]));
        }
        {   // transposed tile: kdT = K[ct][rt] - K[rt][ct]
            const int rt0 = nb + 8 * r4 + 4 * kq;
            const int ct  = mb + l31;
            const s4v k1h = ld4(&nm_hi[ct * LDA + rt0]);
            const s4v k1l = ld4(&nm_lo[ct * LDA + rt0]);
            #pragma unroll
            for (int j = 0; j < 4; ++j)
                kdT[r4][j] = (upbf(k1h[j]) + upbf(k1l[j]))
                           - (upbf(nm_hi[(rt0 + j) * LDA + ct]) +
                              upbf(nm_lo[(rt0 + j) * LDA + ct]));
        }
    }
    #pragma unroll
    for (int i = 0; i < 16; ++i) { acc[i] = 0.f; acct[i] = 0.f; }
    mm32<true, true>(tr_hi, tr_lo, tr_hi, tr_lo, acc, acct, mb, nb, lane);
    __syncthreads();   // K was preloaded; all R reads done -> safe to overwrite
    {
        const float alpha = alp[b], beta = bet[b], dtf = ts[0];
        #pragma unroll
        for (int r4 = 0; r4 < 4; ++r4) {
            {   // X tile -> tr (X^T layout) + xsave
                const int row0 = mb + 8 * r4 + 4 * kq;
                const int col  = nb + l31;
                s4v h4, l4;
                #pragma unroll
                for (int j = 0; j < 4; ++j) {
                    float x = (alpha * kd[r4][j] - beta * acc[4 * r4 + j]) * dtf;
                    if (row0 + j == col) x += 1e-6f;
                    xsave[4 * r4 + j] = x;
                    short hi, lo; splitbf(x, hi, lo);
                    h4[j] = hi; l4[j] = lo;
                }
                st4(&tr_hi[col * LDA + row0], h4);
                st4(&tr_lo[col * LDA + row0], l4);
            }
            {   // X^T tile -> nm (row-major X) + xsaveT
                const int rt0 = nb + 8 * r4 + 4 * kq;
                const int ct  = mb + l31;
                s4v h4, l4;
                #pragma unroll
                for (int j = 0; j < 4; ++j) {
                    float x = (alpha * kdT[r4][j] - beta * acct[4 * r4 + j]) * dtf;
                    if (ct == rt0 + j) x += 1e-6f;
                    xsaveT[4 * r4 + j] = x;
                    short hi, lo; splitbf(x, hi, lo);
                    h4[j] = hi; l4[j] = lo;
                }
                st4(&nm_hi[ct * LDA + rt0], h4);
                st4(&nm_lo[ct * LDA + rt0], l4);
            }
        }
    }
    __syncthreads();

    // ---- Op2': C = X@X (dual); A2 = X/6 + C/24 -> tr; C -> nm;
    //      A1 = I + X + C/2 -> xsave; A1^T -> xsaveT (exact fp32) ----
    #pragma unroll
    for (int i = 0; i < 16; ++i) { acc[i] = 0.f; acct[i] = 0.f; }
    mm32<true, true>(nm_hi, nm_lo, tr_hi, tr_lo, acc, acct, mb, nb, lane);
    __syncthreads();
    #pragma unroll
    for (int r4 = 0; r4 < 4; ++r4) {
        {
            const int row0 = mb + 8 * r4 + 4 * kq;
            const int col  = nb + l31;
            s4v h4, l4;
            #pragma unroll
            for (int j = 0; j < 4; ++j) {
                const float xv = xsave[4 * r4 + j];
                const float cv = acc[4 * r4 + j];
                const float a2 = xv * (1.f / 6.f) + cv * (1.f / 24.f);
                xsave[4 * r4 + j] = ((row0 + j == col) ? 1.f : 0.f) + xv + 0.5f * cv;
                short hi, lo; splitbf(a2, hi, lo);
                h4[j] = hi; l4[j] = lo;
            }
            st4(&tr_hi[col * LDA + row0], h4);        // A2^T
            st4(&tr_lo[col * LDA + row0], l4);
        }
        {
            const int rt0 = nb + 8 * r4 + 4 * kq;
            const int ct  = mb + l31;
            s4v h4, l4;
            #pragma unroll
            for (int j = 0; j < 4; ++j) {
                const float xT = xsaveT[4 * r4 + j];
                const float cT = acct[4 * r4 + j];
                xsaveT[4 * r4 + j] = ((ct == rt0 + j) ? 1.f : 0.f) + xT + 0.5f * cT;
                short hi, lo; splitbf(cT, hi, lo);
                h4[j] = hi; l4[j] = lo;
            }
            st4(&nm_hi[ct * LDA + rt0], h4);          // C row-major
            st4(&nm_lo[ct * LDA + rt0], l4);
        }
    }
    __syncthreads();

    // ---- Op3': M = A1 + C@A2 (dual, seeds = exact A1 / A1^T) -> nm + tr ----
    #pragma unroll
    for (int i = 0; i < 16; ++i) { acc[i] = xsave[i]; acct[i] = xsaveT[i]; }
    mm32<true, true>(nm_hi, nm_lo, tr_hi, tr_lo, acc, acct, mb, nb, lane);
    __syncthreads();
    #pragma unroll
    for (int r4 = 0; r4 < 4; ++r4) {
        {
            const int row0 = mb + 8 * r4 + 4 * kq;
            const int col  = nb + l31;
            s4v h4, l4;
            #pragma unroll
            for (int j = 0; j < 4; ++j) {
                short hi, lo; splitbf(acc[4 * r4 + j], hi, lo);
                h4[j] = hi; l4[j] = lo;
            }
            st4(&tr_hi[col * LDA + row0], h4);        // M^T
            st4(&tr_lo[col * LDA + row0], l4);
        }
        {
            const int rt0 = nb + 8 * r4 + 4 * kq;
            const int ct  = mb + l31;
            s4v h4, l4;
            #pragma unroll
            for (int j = 0; j < 4; ++j) {
                short hi, lo; splitbf(acct[4 * r4 + j], hi, lo);
                h4[j] = hi; l4[j] = lo;
            }
            st4(&nm_hi[ct * LDA + rt0], h4);          // M row-major (packed now)
            st4(&nm_lo[ct * LDA + rt0], l4);
        }
    }
    __syncthreads();

    // ---- seed stages 0..2: FUSED {round (16x16, waves 0-7) + squaring (32x32)} ----
    #pragma unroll
    for (int stage = 0; stage < 3; ++stage) {
        const int J = 1 << stage;
        f4v ar = z4;
        #pragma unroll
        for (int i = 0; i < 16; ++i) { acc[i] = 0.f; acct[i] = 0.f; }
        if (w < 8) {
            #pragma unroll
            for (int kk = 0; kk < DIM; kk += 32) {
                const int ko = kk + quad * 8;
                const s8v rah = ld8(nm_hi + (w * 16 + l15) * LDA + ko);
                const s8v ral = ld8(nm_lo + (w * 16 + l15) * LDA + ko);
                const s8v rbh = ld8(ht_hi + l15 * LDA + ko);
                const s8v rbl = ld8(ht_lo + l15 * LDA + ko);
                ar = mf(rah, rbh, ar);
                ar = mf(rah, rbl, ar);
                ar = mf(ral, rbh, ar);
            }
        }
        mm32<true, true>(nm_hi, nm_lo, tr_hi, tr_lo, acc, acct, mb, nb, lane);
        __syncthreads();
        if (w < 8 && l15 < 2 * J) {
            const int o0 = w * 16 + quad * 4;
            const int sidx = (l15 >> 1) + J - 1;
            s4v h4, l4;
            #pragma unroll
            for (int r = 0; r < 4; ++r) {
                short hi, lo; splitbf(ar[r], hi, lo);
                h4[r] = hi; l4[r] = lo;
                write_out(outF, b, sidx, o0 + r, l15 & 1, ar[r], interleaved, out_size);
            }
            st4(&ht_hi[(l15 + 2 * J) * LDA + o0], h4);
            st4(&ht_lo[(l15 + 2 * J) * LDA + o0], l4);
        }
        #pragma unroll
        for (int r4 = 0; r4 < 4; ++r4) {
            {
                const int row0 = mb + 8 * r4 + 4 * kq;
                const int col  = nb + l31;
                s4v h4, l4;
                #pragma unroll
                for (int j = 0; j < 4; ++j) {
                    short hi, lo; splitbf(acc[4 * r4 + j], hi, lo);
                    h4[j] = hi; l4[j] = lo;
                }
                st4(&tr_hi[col * LDA + row0], h4);
                st4(&tr_lo[col * LDA + row0], l4);
            }
            {
                const int rt0 = nb + 8 * r4 + 4 * kq;
                const int ct  = mb + l31;
                s4v h4, l4;
                #pragma unroll
                for (int j = 0; j < 4; ++j) {
                    short hi, lo; splitbf(acct[4 * r4 + j], hi, lo);
                    h4[j] = hi; l4[j] = lo;
                }
                st4(&nm_hi[ct * LDA + rt0], h4);
                st4(&nm_lo[ct * LDA + rt0], l4);
            }
        }
        __syncthreads();
    }

    // ---- stage 3 (J=8): round + LAST squaring (NM-only: tr never read again) ----
    {
        const int J = 8;
        f4v ar = z4;
        #pragma unroll
        for (int i = 0; i < 16; ++i) acct[i] = 0.f;
        if (w < 8) {
            #pragma unroll
            for (int kk = 0; kk < DIM; kk += 32) {
                const int ko = kk + quad * 8;
                const s8v rah = ld8(nm_hi + (w * 16 + l15) * LDA + ko);
                const s8v ral = ld8(nm_lo + (w * 16 + l15) * LDA + ko);
                const s8v rbh = ld8(ht_hi + l15 * LDA + ko);
                const s8v rbl = ld8(ht_lo + l15 * LDA + ko);
                ar = mf(rah, rbh, ar);
                ar = mf(rah, rbl, ar);
                ar = mf(ral, rbh, ar);
            }
        }
        mm32<false, true>(nm_hi, nm_lo, tr_hi, tr_lo, acc, acct, mb, nb, lane);
        __syncthreads();
        if (w < 8 && l15 < 2 * J) {
            const int o0 = w * 16 + quad * 4;
            const int sidx = (l15 >> 1) + J - 1;
            s4v h4, l4;
            #pragma unroll
            for (int r = 0; r < 4; ++r) {
                short hi, lo; splitbf(ar[r], hi, lo);
                h4[r] = hi; l4[r] = lo;
                write_out(outF, b, sidx, o0 + r, l15 & 1, ar[r], interleaved, out_size);
            }
            st4(&ht_hi[(l15 + 2 * J) * LDA + o0], h4);
            st4(&ht_lo[(l15 + 2 * J) * LDA + o0], l4);
        }
        #pragma unroll
        for (int r4 = 0; r4 < 4; ++r4) {
            const int rt0 = nb + 8 * r4 + 4 * kq;
            const int ct  = mb + l31;
            s4v h4, l4;
            #pragma unroll
            for (int j = 0; j < 4; ++j) {
                short hi, lo; splitbf(acct[4 * r4 + j], hi, lo);
                h4[j] = hi; l4[j] = lo;
            }
            st4(&nm_hi[ct * LDA + rt0], h4);      // V = M^16
            st4(&nm_lo[ct * LDA + rt0], l4);
        }
        __syncthreads();
    }

    // ---- 8 windows: rows <- V @ rows, ping-pong htA <-> htB (htB on dead tr).
    //      One barrier per window. Window 8 = tail (u_128, no LDS writes). ----
    const int sw = w >> 1, ct = w & 1;
    s8v vah[4], val[4];
    #pragma unroll
    for (int k4 = 0; k4 < 4; ++k4) {
        const int ko = k4 * 32 + quad * 8;
        vah[k4] = ld8(nm_hi + (sw * 16 + l15) * LDA + ko);
        val[k4] = ld8(nm_lo + (sw * 16 + l15) * LDA + ko);
    }
    short *rh_hi = ht_hi, *rh_lo = ht_lo;
    short *wh_hi = tr_hi, *wh_lo = tr_lo;
    #pragma unroll
    for (int q = 1; q <= 8; ++q) {
        f4v a2 = z4;
        #pragma unroll
        for (int k4 = 0; k4 < 4; ++k4) {
            const int ko = k4 * 32 + quad * 8;
            const s8v bh = ld8(rh_hi + (ct * 16 + l15) * LDA + ko);
            const s8v bl = ld8(rh_lo + (ct * 16 + l15) * LDA + ko);
            a2 = mf(vah[k4], bh, a2);
            a2 = mf(vah[k4], bl, a2);
            a2 = mf(val[k4], bh, a2);
        }
        {
            const int o0 = sw * 16 + quad * 4;
            const int n = ct * 16 + l15;
            const int sidx = 16 * q + (n >> 1) - 1;
            s4v h4, l4;
            #pragma unroll
            for (int r = 0; r < 4; ++r) {
                short hi, lo; splitbf(a2[r], hi, lo);
                h4[r] = hi; l4[r] = lo;
                if (sidx < SSTEPS)
                    write_out(outF, b, sidx, o0 + r, n & 1, a2[r], interleaved, out_size);
            }
            if (q < 8) {
                st4(&wh_hi[n * LDA + o0], h4);
                st4(&wh_lo[n * LDA + o0], l4);
            }
        }
        __syncthreads();
        short* tp;
        tp = rh_hi; rh_hi = wh_hi; wh_hi = tp;
        tp = rh_lo; rh_lo = wh_lo; wh_lo = tp;
    }
}

// ================= host =================
extern "C" void kernel_launch(void* const* d_in, const int* in_sizes, int n_in,
                              void* d_out, int out_size, void* d_ws, size_t ws_size,
                              hipStream_t stream)
{
    (void)in_sizes; (void)n_in;
    const float* z0r = (const float*)d_in[0];
    const float* z0i = (const float*)d_in[1];
    const float* ts  = (const float*)d_in[2];
    const float* kco = (const float*)d_in[3];
    const float* rco = (const float*)d_in[4];
    const float* alp = (const float*)d_in[5];
    const float* bet = (const float*)d_in[6];
    const float* KB  = (const float*)d_in[7];
    const float* RB  = (const float*)d_in[8];
    float* outF = (float*)d_out;

    const int interleaved = (out_size >= 2 * BATCH * SSTEPS * DIM) ? 1 : 0;
    const size_t ws_needed = (size_t)2 * BATCH * DIM * DIM * sizeof(float);  // 4 MB

    if (d_ws != nullptr && ws_size >= ws_needed) {
        float* ws = (float*)d_ws;
        sum_kr<<<dim3(BATCH * 8), dim3(256), 0, stream>>>(kco, rco, KB, RB, ws);
        htg_mfma<1><<<dim3(BATCH), dim3(1024), 0, stream>>>(
            z0r, z0i, ts, kco, rco, alp, bet, KB, RB, ws, outF, interleaved, out_size);
    } else {
        htg_mfma<0><<<dim3(BATCH), dim3(1024), 0, stream>>>(
            z0r, z0i, ts, kco, rco, alp, bet, KB, RB, nullptr, outF, interleaved, out_size);
    }
}

// Round 7
// 114.930 us; speedup vs baseline: 1.0552x; 1.0447x over previous
//
#include <hip/hip_runtime.h>

#define BATCH   32
#define DIM     128
#define NBASES  8
#define SSTEPS  128
#define LDA     136   // padded row (shorts): 272 B stride, 16B-aligned rows

typedef __attribute__((ext_vector_type(8)))  short s8v;   // 8 bf16 (4 VGPR)
typedef __attribute__((ext_vector_type(4)))  short s4v;   // 4 bf16 (8B packed store)
typedef __attribute__((ext_vector_type(4)))  float f4v;   // 16x16 MFMA acc
typedef __attribute__((ext_vector_type(16))) float f16v;  // 32x32 MFMA acc

__device__ __forceinline__ f4v mf(s8v a, s8v b, f4v c) {
    return __builtin_amdgcn_mfma_f32_16x16x32_bf16(a, b, c, 0, 0, 0);
}
__device__ __forceinline__ f16v mf32(s8v a, s8v b, f16v c) {
    return __builtin_amdgcn_mfma_f32_32x32x16_bf16(a, b, c, 0, 0, 0);
}
__device__ __forceinline__ s8v ld8(const short* p) {
    return *reinterpret_cast<const s8v*>(p);
}
__device__ __forceinline__ s4v ld4(const short* p) {
    return *reinterpret_cast<const s4v*>(p);
}
__device__ __forceinline__ void st4(short* p, s4v v) {
    *reinterpret_cast<s4v*>(p) = v;   // 8B-aligned at all call sites -> ds_write_b64
}
__device__ __forceinline__ float upbf(short h) {
    return __uint_as_float(((unsigned)(unsigned short)h) << 16);
}
// split fp32 -> bf16 hi + bf16 lo (truncation; dropped residual ~2^-16 rel)
__device__ __forceinline__ void splitbf(float v, short& hi, short& lo) {
    const unsigned u = __float_as_uint(v);
    hi = (short)(u >> 16);
    const float fh = __uint_as_float(u & 0xffff0000u);
    lo = (short)(__float_as_uint(v - fh) >> 16);
}

__device__ __forceinline__ void write_out(float* __restrict__ outF, int b, int sidx,
                                          int o, int c, float val,
                                          int interleaved, int out_size)
{
    if (interleaved) {
        const int oi = ((b * SSTEPS + sidx) * DIM + o) * 2 + c;
        if (oi < out_size) outF[oi] = val;
    } else if (c == 0) {
        const int oi = (b * SSTEPS + sidx) * DIM + o;
        if (oi < out_size) outF[oi] = val;
    }
}

// ---- full 128x128x128 split-bf16 MFMA matmul: 16 waves, wave = one 32x32
// v_mfma_f32_32x32x16_bf16 tile. A row-major from "norm" planes, B^T from
// "trans" planes. TRO: acc = C tile. NMO: acct = C^T tile (operand swap on
// the SAME loaded fragments -> no extra LDS reads).
template<bool TRO, bool NMO>
__device__ __forceinline__ void mm32(const short* __restrict__ Ah,
                                     const short* __restrict__ Al,
                                     const short* __restrict__ Bh,
                                     const short* __restrict__ Bl,
                                     f16v& acc, f16v& acct,
                                     int mb, int nb, int lane)
{
    const int l31 = lane & 31, koc = (lane >> 5) * 8;
    #pragma unroll
    for (int ks = 0; ks < 8; ++ks) {
        const int ko = ks * 16 + koc;
        const s8v ah = ld8(Ah + (mb + l31) * LDA + ko);
        const s8v al = ld8(Al + (mb + l31) * LDA + ko);
        const s8v bh = ld8(Bh + (nb + l31) * LDA + ko);
        const s8v bl = ld8(Bl + (nb + l31) * LDA + ko);
        if (TRO) {
            acc = mf32(ah, bh, acc);
            acc = mf32(ah, bl, acc);
            acc = mf32(al, bh, acc);
        }
        if (NMO) {
            acct = mf32(bh, ah, acct);
            acct = mf32(bl, ah, acct);
            acct = mf32(bh, al, acct);
        }
    }
}

// ======== prologue: K_sum / K_sum^T / R_sum^T on 256 blocks -> d_ws ========
// ws layout (fp32): Ks[32][128][128], KsT[32][128][128], RsT[32][128][128] = 6 MB
__global__ __launch_bounds__(256)
void sum_kr(const float* __restrict__ kco, const float* __restrict__ rco,
            const float* __restrict__ KB,  const float* __restrict__ RB,
            float* __restrict__ ws)
{
    const int b = blockIdx.x >> 3, s = blockIdx.x & 7, t = threadIdx.x;
    const int boff = s * 16 * DIM + t * 8;           // row r, cols c..c+7
    const int r = s * 16 + (t >> 4), c = (t & 15) * 8;
    float kc[NBASES], rc[NBASES];
    #pragma unroll
    for (int n = 0; n < NBASES; ++n) {
        kc[n] = kco[b * NBASES + n];
        rc[n] = rco[b * NBASES + n];
    }
    float4 ka = {0.f,0.f,0.f,0.f}, kb4 = {0.f,0.f,0.f,0.f};
    float4 ra = {0.f,0.f,0.f,0.f}, rb4 = {0.f,0.f,0.f,0.f};
    #pragma unroll
    for (int n = 0; n < NBASES; ++n) {
        const float4 k0 = *reinterpret_cast<const float4*>(KB + n * DIM * DIM + boff);
        const float4 k1 = *reinterpret_cast<const float4*>(KB + n * DIM * DIM + boff + 4);
        const float4 r0 = *reinterpret_cast<const float4*>(RB + n * DIM * DIM + boff);
        const float4 r1 = *reinterpret_cast<const float4*>(RB + n * DIM * DIM + boff + 4);
        ka.x += kc[n] * k0.x; ka.y += kc[n] * k0.y; ka.z += kc[n] * k0.z; ka.w += kc[n] * k0.w;
        kb4.x += kc[n] * k1.x; kb4.y += kc[n] * k1.y; kb4.z += kc[n] * k1.z; kb4.w += kc[n] * k1.w;
        ra.x += rc[n] * r0.x; ra.y += rc[n] * r0.y; ra.z += rc[n] * r0.z; ra.w += rc[n] * r0.w;
        rb4.x += rc[n] * r1.x; rb4.y += rc[n] * r1.y; rb4.z += rc[n] * r1.z; rb4.w += rc[n] * r1.w;
    }
    float* Ks  = ws + (size_t)b * DIM * DIM;
    float* KsT = ws + (size_t)BATCH * DIM * DIM + (size_t)b * DIM * DIM;
    float* RsT = ws + (size_t)2 * BATCH * DIM * DIM + (size_t)b * DIM * DIM;
    // K_sum row-major (coalesced)
    *reinterpret_cast<float4*>(Ks + boff)     = ka;
    *reinterpret_cast<float4*>(Ks + boff + 4) = kb4;
    // K_sum^T / R_sum^T: element (r, c+j) -> T[(c+j)*128 + r] (L2-absorbed scatter)
    const float kv[8] = {ka.x, ka.y, ka.z, ka.w, kb4.x, kb4.y, kb4.z, kb4.w};
    const float rv[8] = {ra.x, ra.y, ra.z, ra.w, rb4.x, rb4.y, rb4.z, rb4.w};
    #pragma unroll
    for (int j = 0; j < 8; ++j) {
        KsT[(c + j) * DIM + r] = kv[j];
        RsT[(c + j) * DIM + r] = rv[j];
    }
}

// ============ whole problem: 1 block = 1 batch, MFMA chain in LDS ============
template<int PRE>
__global__ __launch_bounds__(1024) __attribute__((amdgpu_waves_per_eu(4, 4)))
void htg_mfma(const float* __restrict__ z0r, const float* __restrict__ z0i,
              const float* __restrict__ ts,  const float* __restrict__ kco,
              const float* __restrict__ rco, const float* __restrict__ alp,
              const float* __restrict__ bet, const float* __restrict__ KB,
              const float* __restrict__ RB,  const float* __restrict__ wsum,
              float* __restrict__ outF, int interleaved, int out_size)
{
    __shared__ short nm_hi[DIM * LDA], nm_lo[DIM * LDA];   // row-major planes
    __shared__ short tr_hi[DIM * LDA], tr_lo[DIM * LDA];   // transposed planes
    __shared__ short ht_hi[32 * LDA],  ht_lo[32 * LDA];    // u-table A

    const int b = blockIdx.x, t = threadIdx.x;
    const int w = t >> 6, lane = t & 63;
    const int l15 = lane & 15, quad = lane >> 4;            // 16x16 paths
    const int l31 = lane & 31, kq = lane >> 5;              // 32x32 paths
    const f4v z4 = {0.f, 0.f, 0.f, 0.f};
    const int mb = (w & 3) * 32, nb = (w >> 2) * 32;        // 4x4 grid of 32x32

    // ---- S1 ----
    if (PRE) {
        // tr = R^T from RsT (row-major read -> PACKED row-major st4, no scatter).
        // K is NOT staged in LDS at all (kd comes from global Ks/KsT in Op1).
        const float* RsT = wsum + (size_t)2 * BATCH * DIM * DIM + (size_t)b * DIM * DIM;
        #pragma unroll
        for (int q = 0; q < 4; ++q) {
            const int e = q * 4096 + t * 4;
            const float4 rv = *reinterpret_cast<const float4*>(RsT + e);
            const int row = e >> 7, colr = e & 127;      // tr row (=orig col), cols
            const float rr[4] = {rv.x, rv.y, rv.z, rv.w};
            s4v h4, l4;
            #pragma unroll
            for (int j = 0; j < 4; ++j) {
                short hi, lo; splitbf(rr[j], hi, lo);
                h4[j] = hi; l4[j] = lo;
            }
            st4(&tr_hi[row * LDA + colr], h4);
            st4(&tr_lo[row * LDA + colr], l4);
        }
        if (t < 2 * DIM) {
            const int c = t >> 7, o = t & 127;
            const float zv = (c == 0) ? z0r[b * DIM + o] : z0i[b * DIM + o];
            short hi, lo; splitbf(zv, hi, lo);
            ht_hi[c * LDA + o] = hi; ht_lo[c * LDA + o] = lo;
        }
    } else {
        float rc[NBASES], kc[NBASES];
        #pragma unroll
        for (int n = 0; n < NBASES; ++n) {
            rc[n] = rco[b * NBASES + n];
            kc[n] = kco[b * NBASES + n];
        }
        #pragma unroll
        for (int q = 0; q < 4; ++q) {
            const int e = q * 4096 + t * 4;
            float4 r4 = {0.f, 0.f, 0.f, 0.f}, k4 = {0.f, 0.f, 0.f, 0.f};
            #pragma unroll
            for (int n = 0; n < NBASES; ++n) {
                const float4 rvv = *reinterpret_cast<const float4*>(RB + n * DIM * DIM + e);
                const float4 kvv = *reinterpret_cast<const float4*>(KB + n * DIM * DIM + e);
                r4.x += rc[n] * rvv.x; r4.y += rc[n] * rvv.y;
                r4.z += rc[n] * rvv.z; r4.w += rc[n] * rvv.w;
                k4.x += kc[n] * kvv.x; k4.y += kc[n] * kvv.y;
                k4.z += kc[n] * kvv.z; k4.w += kc[n] * kvv.w;
            }
            const int r = e >> 7, c = e & 127;
            const float rr[4] = {r4.x, r4.y, r4.z, r4.w};
            const float kk[4] = {k4.x, k4.y, k4.z, k4.w};
            s4v kh, kl;
            #pragma unroll
            for (int j = 0; j < 4; ++j) {
                short hi, lo;
                splitbf(rr[j], hi, lo);
                tr_hi[(c + j) * LDA + r] = hi; tr_lo[(c + j) * LDA + r] = lo;
                splitbf(kk[j], hi, lo);
                kh[j] = hi; kl[j] = lo;
            }
            st4(&nm_hi[r * LDA + c], kh);
            st4(&nm_lo[r * LDA + c], kl);
        }
        if (t < 2 * DIM) {
            const int c = t >> 7, o = t & 127;
            const float zv = (c == 0) ? z0r[b * DIM + o] : z0i[b * DIM + o];
            short hi, lo; splitbf(zv, hi, lo);
            ht_hi[c * LDA + o] = hi; ht_lo[c * LDA + o] = lo;
        }
    }
    __syncthreads();

    f16v acc, acct;
    float xsave[16];    // Op1: X tile; after Op2': A1 tile
    float xsaveT[16];   // Op1: X^T tile; after Op2': A1^T tile

    // ---- Op1: gram = R^T@R (dual). kd/kdT preloaded BEFORE the mm:
    //      PRE=1 -> coalesced global reads of Ks/KsT (hidden under the mm);
    //      PRE=0 -> legacy LDS reads of staged K. ----
    float kd[4][4], kdT[4][4];
    if (PRE) {
        const float* Ks  = wsum + (size_t)b * DIM * DIM;
        const float* KsT = wsum + (size_t)BATCH * DIM * DIM + (size_t)b * DIM * DIM;
        #pragma unroll
        for (int r4 = 0; r4 < 4; ++r4) {
            const int row0 = mb + 8 * r4 + 4 * kq;
            const int col  = nb + l31;
            const int rt0  = nb + 8 * r4 + 4 * kq;
            const int ct   = mb + l31;
            #pragma unroll
            for (int j = 0; j < 4; ++j) {
                // kd  = K[row][col] - K[col][row], both terms row-major coalesced
                kd[r4][j]  = Ks[(row0 + j) * DIM + col] - KsT[(row0 + j) * DIM + col];
                // kdT = K[ct][rt] - K[rt][ct] = KsT[rt][ct] - Ks[rt][ct]
                kdT[r4][j] = KsT[(rt0 + j) * DIM + ct]  - Ks[(rt0 + j) * DIM + ct];
            }
        }
    } else {
        #pragma unroll
        for (int r4 = 0; r4 < 4; ++r4) {
            {
                const int row0 = mb + 8 * r4 + 4 * kq;
                const int col  = nb + l31;
                const s4v k2h = ld4(&nm_hi[col * LDA + row0]);
                const s4v k2l = ld4(&nm_lo[col * LDA + row0]);
                #pragma unroll
                for (int j = 0; j < 4; ++j)
                    kd[r4][j] = (upbf(nm_hi[(row0 + j) * LDA + col]) +
                                 upbf(nm_lo[(row0 + j) * LDA + col]))
                              - (upbf(k2h[j]) + upbf(k2l[j]));
            }
            {
                const int rt0 = nb + 8 * r4 + 4 * kq;
                const int ct  = mb + l31;
                const s4v k1h = ld4(&nm_hi[ct * LDA + rt0]);
                const s4v k1l = ld4(&nm_lo[ct * LDA + rt0]);
                #pragma unroll
                for (int j = 0; j < 4; ++j)
                    kdT[r4][j] = (upbf(k1h[j]) + upbf(k1l[j]))
                               - (upbf(nm_hi[(rt0 + j) * LDA + ct]) +
                                  upbf(nm_lo[(rt0 + j) * LDA + ct]));
            }
        }
    }
    #pragma unroll
    for (int i = 0; i < 16; ++i) { acc[i] = 0.f; acct[i] = 0.f; }
    mm32<true, true>(tr_hi, tr_lo, tr_hi, tr_lo, acc, acct, mb, nb, lane);
    __syncthreads();   // all R (and legacy K) reads done -> safe to overwrite
    {
        const float alpha = alp[b], beta = bet[b], dtf = ts[0];
        #pragma unroll
        for (int r4 = 0; r4 < 4; ++r4) {
            {   // X tile -> tr (X^T layout) + xsave
                const int row0 = mb + 8 * r4 + 4 * kq;
                const int col  = nb + l31;
                s4v h4, l4;
                #pragma unroll
                for (int j = 0; j < 4; ++j) {
                    float x = (alpha * kd[r4][j] - beta * acc[4 * r4 + j]) * dtf;
                    if (row0 + j == col) x += 1e-6f;
                    xsave[4 * r4 + j] = x;
                    short hi, lo; splitbf(x, hi, lo);
                    h4[j] = hi; l4[j] = lo;
                }
                st4(&tr_hi[col * LDA + row0], h4);
                st4(&tr_lo[col * LDA + row0], l4);
            }
            {   // X^T tile -> nm (row-major X) + xsaveT
                const int rt0 = nb + 8 * r4 + 4 * kq;
                const int ct  = mb + l31;
                s4v h4, l4;
                #pragma unroll
                for (int j = 0; j < 4; ++j) {
                    float x = (alpha * kdT[r4][j] - beta * acct[4 * r4 + j]) * dtf;
                    if (ct == rt0 + j) x += 1e-6f;
                    xsaveT[4 * r4 + j] = x;
                    short hi, lo; splitbf(x, hi, lo);
                    h4[j] = hi; l4[j] = lo;
                }
                st4(&nm_hi[ct * LDA + rt0], h4);
                st4(&nm_lo[ct * LDA + rt0], l4);
            }
        }
    }
    __syncthreads();

    // ---- Op2': C = X@X (dual); A2 = X/6 + C/24 -> tr; C -> nm;
    //      A1 = I + X + C/2 -> xsave; A1^T -> xsaveT (exact fp32) ----
    #pragma unroll
    for (int i = 0; i < 16; ++i) { acc[i] = 0.f; acct[i] = 0.f; }
    mm32<true, true>(nm_hi, nm_lo, tr_hi, tr_lo, acc, acct, mb, nb, lane);
    __syncthreads();
    #pragma unroll
    for (int r4 = 0; r4 < 4; ++r4) {
        {
            const int row0 = mb + 8 * r4 + 4 * kq;
            const int col  = nb + l31;
            s4v h4, l4;
            #pragma unroll
            for (int j = 0; j < 4; ++j) {
                const float xv = xsave[4 * r4 + j];
                const float cv = acc[4 * r4 + j];
                const float a2 = xv * (1.f / 6.f) + cv * (1.f / 24.f);
                xsave[4 * r4 + j] = ((row0 + j == col) ? 1.f : 0.f) + xv + 0.5f * cv;
                short hi, lo; splitbf(a2, hi, lo);
                h4[j] = hi; l4[j] = lo;
            }
            st4(&tr_hi[col * LDA + row0], h4);        // A2^T
            st4(&tr_lo[col * LDA + row0], l4);
        }
        {
            const int rt0 = nb + 8 * r4 + 4 * kq;
            const int ct  = mb + l31;
            s4v h4, l4;
            #pragma unroll
            for (int j = 0; j < 4; ++j) {
                const float xT = xsaveT[4 * r4 + j];
                const float cT = acct[4 * r4 + j];
                xsaveT[4 * r4 + j] = ((ct == rt0 + j) ? 1.f : 0.f) + xT + 0.5f * cT;
                short hi, lo; splitbf(cT, hi, lo);
                h4[j] = hi; l4[j] = lo;
            }
            st4(&nm_hi[ct * LDA + rt0], h4);          // C row-major
            st4(&nm_lo[ct * LDA + rt0], l4);
        }
    }
    __syncthreads();

    // ---- Op3': M = A1 + C@A2 (dual, seeds = exact A1 / A1^T) -> nm + tr ----
    #pragma unroll
    for (int i = 0; i < 16; ++i) { acc[i] = xsave[i]; acct[i] = xsaveT[i]; }
    mm32<true, true>(nm_hi, nm_lo, tr_hi, tr_lo, acc, acct, mb, nb, lane);
    __syncthreads();
    #pragma unroll
    for (int r4 = 0; r4 < 4; ++r4) {
        {
            const int row0 = mb + 8 * r4 + 4 * kq;
            const int col  = nb + l31;
            s4v h4, l4;
            #pragma unroll
            for (int j = 0; j < 4; ++j) {
                short hi, lo; splitbf(acc[4 * r4 + j], hi, lo);
                h4[j] = hi; l4[j] = lo;
            }
            st4(&tr_hi[col * LDA + row0], h4);        // M^T
            st4(&tr_lo[col * LDA + row0], l4);
        }
        {
            const int rt0 = nb + 8 * r4 + 4 * kq;
            const int ct  = mb + l31;
            s4v h4, l4;
            #pragma unroll
            for (int j = 0; j < 4; ++j) {
                short hi, lo; splitbf(acct[4 * r4 + j], hi, lo);
                h4[j] = hi; l4[j] = lo;
            }
            st4(&nm_hi[ct * LDA + rt0], h4);          // M row-major
            st4(&nm_lo[ct * LDA + rt0], l4);
        }
    }
    __syncthreads();

    // ---- seed stages 0..2: FUSED {round (16x16, waves 0-7) + squaring (32x32)} ----
    #pragma unroll
    for (int stage = 0; stage < 3; ++stage) {
        const int J = 1 << stage;
        f4v ar = z4;
        #pragma unroll
        for (int i = 0; i < 16; ++i) { acc[i] = 0.f; acct[i] = 0.f; }
        if (w < 8) {
            #pragma unroll
            for (int kk = 0; kk < DIM; kk += 32) {
                const int ko = kk + quad * 8;
                const s8v rah = ld8(nm_hi + (w * 16 + l15) * LDA + ko);
                const s8v ral = ld8(nm_lo + (w * 16 + l15) * LDA + ko);
                const s8v rbh = ld8(ht_hi + l15 * LDA + ko);
                const s8v rbl = ld8(ht_lo + l15 * LDA + ko);
                ar = mf(rah, rbh, ar);
                ar = mf(rah, rbl, ar);
                ar = mf(ral, rbh, ar);
            }
        }
        mm32<true, true>(nm_hi, nm_lo, tr_hi, tr_lo, acc, acct, mb, nb, lane);
        __syncthreads();
        if (w < 8 && l15 < 2 * J) {
            const int o0 = w * 16 + quad * 4;
            const int sidx = (l15 >> 1) + J - 1;
            s4v h4, l4;
            #pragma unroll
            for (int r = 0; r < 4; ++r) {
                short hi, lo; splitbf(ar[r], hi, lo);
                h4[r] = hi; l4[r] = lo;
                write_out(outF, b, sidx, o0 + r, l15 & 1, ar[r], interleaved, out_size);
            }
            st4(&ht_hi[(l15 + 2 * J) * LDA + o0], h4);
            st4(&ht_lo[(l15 + 2 * J) * LDA + o0], l4);
        }
        #pragma unroll
        for (int r4 = 0; r4 < 4; ++r4) {
            {
                const int row0 = mb + 8 * r4 + 4 * kq;
                const int col  = nb + l31;
                s4v h4, l4;
                #pragma unroll
                for (int j = 0; j < 4; ++j) {
                    short hi, lo; splitbf(acc[4 * r4 + j], hi, lo);
                    h4[j] = hi; l4[j] = lo;
                }
                st4(&tr_hi[col * LDA + row0], h4);
                st4(&tr_lo[col * LDA + row0], l4);
            }
            {
                const int rt0 = nb + 8 * r4 + 4 * kq;
                const int ct  = mb + l31;
                s4v h4, l4;
                #pragma unroll
                for (int j = 0; j < 4; ++j) {
                    short hi, lo; splitbf(acct[4 * r4 + j], hi, lo);
                    h4[j] = hi; l4[j] = lo;
                }
                st4(&nm_hi[ct * LDA + rt0], h4);
                st4(&nm_lo[ct * LDA + rt0], l4);
            }
        }
        __syncthreads();
    }

    // ---- stage 3 (J=8): round + LAST squaring (NM-only; tr dies here) ----
    {
        const int J = 8;
        f4v ar = z4;
        #pragma unroll
        for (int i = 0; i < 16; ++i) acct[i] = 0.f;
        if (w < 8) {
            #pragma unroll
            for (int kk = 0; kk < DIM; kk += 32) {
                const int ko = kk + quad * 8;
                const s8v rah = ld8(nm_hi + (w * 16 + l15) * LDA + ko);
                const s8v ral = ld8(nm_lo + (w * 16 + l15) * LDA + ko);
                const s8v rbh = ld8(ht_hi + l15 * LDA + ko);
                const s8v rbl = ld8(ht_lo + l15 * LDA + ko);
                ar = mf(rah, rbh, ar);
                ar = mf(rah, rbl, ar);
                ar = mf(ral, rbh, ar);
            }
        }
        mm32<false, true>(nm_hi, nm_lo, tr_hi, tr_lo, acc, acct, mb, nb, lane);
        __syncthreads();
        if (w < 8 && l15 < 2 * J) {
            const int o0 = w * 16 + quad * 4;
            const int sidx = (l15 >> 1) + J - 1;
            s4v h4, l4;
            #pragma unroll
            for (int r = 0; r < 4; ++r) {
                short hi, lo; splitbf(ar[r], hi, lo);
                h4[r] = hi; l4[r] = lo;
                write_out(outF, b, sidx, o0 + r, l15 & 1, ar[r], interleaved, out_size);
            }
            st4(&ht_hi[(l15 + 2 * J) * LDA + o0], h4);
            st4(&ht_lo[(l15 + 2 * J) * LDA + o0], l4);
        }
        #pragma unroll
        for (int r4 = 0; r4 < 4; ++r4) {
            const int rt0 = nb + 8 * r4 + 4 * kq;
            const int ct  = mb + l31;
            s4v h4, l4;
            #pragma unroll
            for (int j = 0; j < 4; ++j) {
                short hi, lo; splitbf(acct[4 * r4 + j], hi, lo);
                h4[j] = hi; l4[j] = lo;
            }
            st4(&nm_hi[ct * LDA + rt0], h4);      // V = M^16
            st4(&nm_lo[ct * LDA + rt0], l4);
        }
        __syncthreads();
    }

    // ---- 8 windows: rows <- V @ rows, ping-pong htA <-> htB (htB on dead tr).
    //      One barrier per window. Window 8 = tail (u_128, no LDS writes). ----
    const int sw = w >> 1, ct = w & 1;
    s8v vah[4], val[4];
    #pragma unroll
    for (int k4 = 0; k4 < 4; ++k4) {
        const int ko = k4 * 32 + quad * 8;
        vah[k4] = ld8(nm_hi + (sw * 16 + l15) * LDA + ko);
        val[k4] = ld8(nm_lo + (sw * 16 + l15) * LDA + ko);
    }
    short *rh_hi = ht_hi, *rh_lo = ht_lo;
    short *wh_hi = tr_hi, *wh_lo = tr_lo;
    #pragma unroll
    for (int q = 1; q <= 8; ++q) {
        f4v a2 = z4;
        #pragma unroll
        for (int k4 = 0; k4 < 4; ++k4) {
            const int ko = k4 * 32 + quad * 8;
            const s8v bh = ld8(rh_hi + (ct * 16 + l15) * LDA + ko);
            const s8v bl = ld8(rh_lo + (ct * 16 + l15) * LDA + ko);
            a2 = mf(vah[k4], bh, a2);
            a2 = mf(vah[k4], bl, a2);
            a2 = mf(val[k4], bh, a2);
        }
        {
            const int o0 = sw * 16 + quad * 4;
            const int n = ct * 16 + l15;
            const int sidx = 16 * q + (n >> 1) - 1;
            s4v h4, l4;
            #pragma unroll
            for (int r = 0; r < 4; ++r) {
                short hi, lo; splitbf(a2[r], hi, lo);
                h4[r] = hi; l4[r] = lo;
                if (sidx < SSTEPS)
                    write_out(outF, b, sidx, o0 + r, n & 1, a2[r], interleaved, out_size);
            }
            if (q < 8) {
                st4(&wh_hi[n * LDA + o0], h4);
                st4(&wh_lo[n * LDA + o0], l4);
            }
        }
        __syncthreads();
        short* tp;
        tp = rh_hi; rh_hi = wh_hi; wh_hi = tp;
        tp = rh_lo; rh_lo = wh_lo; wh_lo = tp;
    }
}

// ================= host =================
extern "C" void kernel_launch(void* const* d_in, const int* in_sizes, int n_in,
                              void* d_out, int out_size, void* d_ws, size_t ws_size,
                              hipStream_t stream)
{
    (void)in_sizes; (void)n_in;
    const float* z0r = (const float*)d_in[0];
    const float* z0i = (const float*)d_in[1];
    const float* ts  = (const float*)d_in[2];
    const float* kco = (const float*)d_in[3];
    const float* rco = (const float*)d_in[4];
    const float* alp = (const float*)d_in[5];
    const float* bet = (const float*)d_in[6];
    const float* KB  = (const float*)d_in[7];
    const float* RB  = (const float*)d_in[8];
    float* outF = (float*)d_out;

    const int interleaved = (out_size >= 2 * BATCH * SSTEPS * DIM) ? 1 : 0;
    const size_t ws_needed = (size_t)3 * BATCH * DIM * DIM * sizeof(float);  // 6 MB

    if (d_ws != nullptr && ws_size >= ws_needed) {
        float* ws = (float*)d_ws;
        sum_kr<<<dim3(BATCH * 8), dim3(256), 0, stream>>>(kco, rco, KB, RB, ws);
        htg_mfma<1><<<dim3(BATCH), dim3(1024), 0, stream>>>(
            z0r, z0i, ts, kco, rco, alp, bet, KB, RB, ws, outF, interleaved, out_size);
    } else {
        htg_mfma<0><<<dim3(BATCH), dim3(1024), 0, stream>>>(
            z0r, z0i, ts, kco, rco, alp, bet, KB, RB, nullptr, outF, interleaved, out_size);
    }
}